// Round 1
// baseline (62208.978 us; speedup 1.0000x reference)
//
#include <hip/hip_runtime.h>

#define BB 8
#define CC 96
#define TT 1000
#define FF 64
#define LL 12
// gates: 3*CC = 288 output rows per projection

__device__ __forceinline__ float sigmoidf_(float v) {
    return 1.0f / (1.0f + __expf(-v));
}

// One block = one (cell, b): all 64 f-columns, all 288 gate rows.
// 512 threads = 8 waves. lane (0..63) = f column. Wave wv owns output
// channels co = wv*12 .. wv*12+11 (and their 3 gate rows each).
// All weight/bias addresses are wave-uniform (readfirstlane on wave id),
// so they take the scalar (s_load) path: LDS carries only activations and
// the matmul inner loop is pure VALU (v_fmac with SGPR weight operand).

__global__ __launch_bounds__(512) void cell_diag(
    const float* __restrict__ x,
    const float* __restrict__ inw_all,
    const float* __restrict__ hnw_all,
    const float* __restrict__ xw_all,
    const float* __restrict__ xb_all,
    const float* __restrict__ hw_all,
    const float* __restrict__ hb_all,
    const float* __restrict__ pw_all,
    const float* __restrict__ pb_all,
    const float* __restrict__ onw_all,
    float* __restrict__ out,
    float* __restrict__ H,     // [2][LL][BB][CC][FF] ping-pong state
    int d, int l_start)
{
    const int cell = blockIdx.x >> 3;
    const int b    = blockIdx.x & 7;
    const int l = l_start + cell;
    const int t = d - l;

    const int tid  = threadIdx.x;
    const int lane = tid & 63;
    const int wv   = __builtin_amdgcn_readfirstlane(tid >> 6);   // 0..7, uniform
    const int co0  = wv * 12;

    __shared__ float hpn[CC][66];   // rms(hp) with f-halo; reused afterwards as ya
    __shared__ float ha[CC][FF];    // dwconv output (hg matmul input)
    __shared__ float sred[2][8][64];
    __shared__ float s_y[64];
    __shared__ float s_h[64];

    const float* inw = inw_all + l*CC;
    const float* hnw = hnw_all + l*CC;
    const float* xw  = xw_all + (size_t)l*288*CC;
    const float* xb  = xb_all + l*288;
    const float* hw  = hw_all + l*CC*3;
    const float* hb  = hb_all + l*CC;
    const float* pw  = pw_all + (size_t)l*288*CC;
    const float* pb  = pb_all + l*288;
    const float* onw = onw_all + l*CC;

    // Both y (layer l-1 @ t) and hp (layer l @ t-1) were produced on diag d-1.
    const int bufW = d & 1;
    const int bufR = (d + 1) & 1;

    // ---- Phase A: load this wave's 12 y rows and 12 hp rows into registers ----
    const float* ysrc; size_t ystride;
    if (l == 0) { ysrc = x + (size_t)b*CC*TT*FF + (size_t)t*FF; ystride = (size_t)TT*FF; }
    else        { ysrc = H + ((((size_t)bufR*LL + (l-1))*BB + b)*CC)*FF; ystride = FF; }
    const float* hpsrc = H + ((((size_t)bufR*LL + l)*BB + b)*CC)*FF;

    float yreg[12], hreg[12];
    float ssy = 0.f, ssh = 0.f;
    #pragma unroll
    for (int i = 0; i < 12; i++) {
        const int c = co0 + i;
        float yv = ysrc[(size_t)c*ystride + lane];
        float hv = (t > 0) ? hpsrc[(size_t)c*FF + lane] : 0.0f;
        yreg[i] = yv; hreg[i] = hv;
        ssy += yv*yv; ssh += hv*hv;
    }
    sred[0][wv][lane] = ssy;
    sred[1][wv][lane] = ssh;
    __syncthreads();

    // ---- per-column RMS stats (reduce the 8 wave partials) ----
    if (tid < 64) {
        float s = 0.f;
        #pragma unroll
        for (int w = 0; w < 8; w++) s += sred[0][w][tid];
        s_y[tid] = rsqrtf(s * (1.0f/CC) + 1e-6f);
    } else if (tid < 128) {
        const int j = tid - 64;
        float s = 0.f;
        #pragma unroll
        for (int w = 0; w < 8; w++) s += sred[1][w][j];
        s_h[j] = rsqrtf(s * (1.0f/CC) + 1e-6f);
    }
    __syncthreads();

    const float syl = s_y[lane];
    const float shl = s_h[lane];

    // ---- Phase B: hpn = hp * s_h (per-column), halo cols 0 and 65 = 0 ----
    #pragma unroll
    for (int i = 0; i < 12; i++)
        hpn[co0+i][1+lane] = hreg[i] * shl;
    if (lane < 2) {
        #pragma unroll
        for (int i = 0; i < 12; i++) hpn[co0+i][lane*65] = 0.f;
    }
    __syncthreads();

    // depthwise conv K=3 along f, then *hnw + hb  (hnw factors out of the conv)
    #pragma unroll
    for (int i = 0; i < 12; i++) {
        const int c = co0 + i;
        const float w0 = hw[c*3+0], w1 = hw[c*3+1], w2 = hw[c*3+2];
        ha[c][lane] = (w0*hpn[c][lane] + w1*hpn[c][lane+1] + w2*hpn[c][lane+2])
                      * hnw[c] + hb[c];
    }
    __syncthreads();   // all conv reads of hpn done -> reuse hpn as ya
    #pragma unroll
    for (int i = 0; i < 12; i++) {
        const int c = co0 + i;
        hpn[c][lane] = yreg[i] * syl * inw[c];
    }
    __syncthreads();

    // ---- Matmuls: xg = xw @ ya, hg = pw @ ha ----
    // Weight float4s are wave-uniform -> s_load_dwordx4; inputs are full-row
    // ds_read_b32 (2 lanes/bank, conflict-free). 48 FMAs per 4 LDS reads.
    float accx[3][12], accp[3][12];
    #pragma unroll
    for (int g = 0; g < 3; g++)
        #pragma unroll
        for (int i = 0; i < 12; i++) { accx[g][i] = 0.f; accp[g][i] = 0.f; }

    #pragma unroll
    for (int g = 0; g < 3; g++) {
        const float* xwb = xw + (size_t)(g*CC + co0)*CC;
        #pragma unroll 4
        for (int kc = 0; kc < CC; kc += 4) {
            const float a0 = hpn[kc+0][lane];
            const float a1 = hpn[kc+1][lane];
            const float a2 = hpn[kc+2][lane];
            const float a3 = hpn[kc+3][lane];
            #pragma unroll
            for (int i = 0; i < 12; i++) {
                const float4 w4 = *(const float4*)(xwb + (size_t)i*CC + kc);
                accx[g][i] += w4.x*a0 + w4.y*a1 + w4.z*a2 + w4.w*a3;
            }
        }
        const float* pwb = pw + (size_t)(g*CC + co0)*CC;
        #pragma unroll 4
        for (int kc = 0; kc < CC; kc += 4) {
            const float a0 = ha[kc+0][lane];
            const float a1 = ha[kc+1][lane];
            const float a2 = ha[kc+2][lane];
            const float a3 = ha[kc+3][lane];
            #pragma unroll
            for (int i = 0; i < 12; i++) {
                const float4 w4 = *(const float4*)(pwb + (size_t)i*CC + kc);
                accp[g][i] += w4.x*a0 + w4.y*a1 + w4.z*a2 + w4.w*a3;
            }
        }
    }

    // ---- GRU epilogue (in-register; hp already in hreg, y in yreg) ----
    float v[12];
    float sso = 0.f;
    #pragma unroll
    for (int i = 0; i < 12; i++) {
        const int c = co0 + i;
        const float xbr = xb[c], xbz = xb[c+96], xbn = xb[c+192];
        const float pbr = pb[c], pbz = pb[c+96], pbn = pb[c+192];
        const float r  = sigmoidf_(accx[0][i] + xbr + accp[0][i] + pbr);
        const float z  = sigmoidf_(accx[1][i] + xbz + accp[1][i] + pbz);
        const float cn = tanhf(accx[2][i] + xbn + r * (accp[2][i] + pbn));
        const float hnew = (1.0f - z) * cn + z * hreg[i];
        const float vv = hnew + yreg[i];
        v[i] = vv;
        sso += vv*vv;
    }
    sred[0][wv][lane] = sso;
    __syncthreads();

    // ---- out_norm stats ----
    if (tid < 64) {
        float s = 0.f;
        #pragma unroll
        for (int w = 0; w < 8; w++) s += sred[0][w][tid];
        s_y[tid] = rsqrtf(s * (1.0f/CC) + 1e-6f);
    }
    __syncthreads();
    const float sol = s_y[lane];

    // ---- write state (and final output for last layer) ----
    float* hdst = H + ((((size_t)bufW*LL + l)*BB + b)*CC)*FF;
    #pragma unroll
    for (int i = 0; i < 12; i++) {
        const int c = co0 + i;
        hdst[(size_t)c*FF + lane] = v[i] * sol * onw[c];
    }
    if (l == LL-1) {
        float* odst = out + (size_t)b*CC*TT*FF + (size_t)t*FF;
        #pragma unroll
        for (int i = 0; i < 12; i++) {
            const int c = co0 + i;
            odst[(size_t)c*TT*FF + lane] = v[i] * sol * onw[c];
        }
    }
}

extern "C" void kernel_launch(void* const* d_in, const int* in_sizes, int n_in,
                              void* d_out, int out_size, void* d_ws, size_t ws_size,
                              hipStream_t stream) {
    const float* x   = (const float*)d_in[0];
    const float* inw = (const float*)d_in[1];
    const float* hnw = (const float*)d_in[2];
    const float* xw  = (const float*)d_in[3];
    const float* xb  = (const float*)d_in[4];
    const float* hw  = (const float*)d_in[5];
    const float* hb  = (const float*)d_in[6];
    const float* pw  = (const float*)d_in[7];
    const float* pb  = (const float*)d_in[8];
    const float* onw = (const float*)d_in[9];
    float* out = (float*)d_out;
    float* H   = (float*)d_ws;   // needs 2*LL*BB*CC*FF*4 = 4.72 MB

    // wavefront over anti-diagonals d = l + t
    for (int d = 0; d < TT + LL - 1; d++) {
        int l_lo = d - (TT - 1); if (l_lo < 0) l_lo = 0;
        int l_hi = d;            if (l_hi > LL - 1) l_hi = LL - 1;
        int nact = l_hi - l_lo + 1;
        cell_diag<<<dim3(nact * 8), dim3(512), 0, stream>>>(
            x, inw, hnw, xw, xb, hw, hb, pw, pb, onw, out, H, d, l_lo);
    }
}

// Round 4
// 38486.096 us; speedup vs baseline: 1.6164x; 1.6164x over previous
//
#include <hip/hip_runtime.h>

#define BB 8
#define CC 96
#define TT 1000
#define FF 64
#define LL 12
#define EPSF 1e-6f

__device__ __forceinline__ float sigmoidf_(float v) {
    return 1.0f / (1.0f + __expf(-v));
}

// One block = (cell on diagonal, b, row-half). 256 threads, 4 waves.
// Block computes 144 of the 288 gate rows for all 64 f-columns.
// H stores UN-normalized v = h_new + y; consumers recompute the out-norm
// rsqrt from the raw values they load anyway (deferred normalization).
// Weights are read directly from global (L2-resident, 2.65 MB total):
// no weight staging, no in-matmul barriers.
__global__ __launch_bounds__(256, 1) void cell_diag(
    const float* __restrict__ x,
    const float* __restrict__ inw_all,
    const float* __restrict__ hnw_all,
    const float* __restrict__ xw_all,
    const float* __restrict__ xb_all,
    const float* __restrict__ hw_all,
    const float* __restrict__ hb_all,
    const float* __restrict__ pw_all,
    const float* __restrict__ pb_all,
    const float* __restrict__ onw_all,
    float* __restrict__ out,
    float* __restrict__ H,      // [2][LL][BB][CC][FF] un-normalized states
    int d, int l_start)
{
    const int cell = blockIdx.x >> 4;
    const int sub  = blockIdx.x & 15;
    const int l    = l_start + cell;
    const int t    = d - l;
    const int b    = sub >> 1;
    const int half = sub & 1;
    const int ch0  = half * 48;

    __shared__ float Ay[CC][FF];       // rms(y)*inw  (xg matmul input)
    __shared__ float Ah[CC][FF];       // dwconv output (hg matmul input)
    __shared__ float sred[2][4][64];
    __shared__ float s_pn[64];         // producer out-norm rsqrt per column
    __shared__ float s_hn[64];         // self out-norm rsqrt per column

    const int tid  = threadIdx.x;
    const int lane = tid & 63;
    const int wv   = tid >> 6;         // 0..3

    const float* inw = inw_all + l*CC;
    const float* hnw = hnw_all + l*CC;
    const float* xw  = xw_all + (size_t)l*288*CC;
    const float* xb  = xb_all + l*288;
    const float* hw  = hw_all + l*CC*3;
    const float* hb  = hb_all + l*CC;
    const float* pw  = pw_all + (size_t)l*288*CC;
    const float* pb  = pb_all + l*288;
    const float* onw = onw_all + l*CC;
    const float* onw_prev = onw_all + (l > 0 ? (l-1)*CC : 0);

    const int parW = d & 1, parR = parW ^ 1;
    const float* Hprev = H + (((size_t)parR*LL + (l > 0 ? l-1 : 0))*BB + b)*CC*FF;
    const float* Hself = H + (((size_t)parR*LL + l)*BB + b)*CC*FF;

    // ---- phase 1a: raw loads + raw sum-of-squares (for deferred norms) ----
    float yr[24], hr[24];
    {
        float sp = 0.f, sh = 0.f;
        #pragma unroll
        for (int i = 0; i < 24; i++) {
            const int c = wv*24 + i;
            float yv = (l == 0) ? x[(((size_t)b*CC + c)*TT + t)*FF + lane]
                                : Hprev[(size_t)c*FF + lane];
            float hv = (t > 0) ? Hself[(size_t)c*FF + lane] : 0.0f;
            yr[i] = yv; hr[i] = hv;
            sp += yv*yv; sh += hv*hv;
        }
        sred[0][wv][lane] = sp;
        sred[1][wv][lane] = sh;
    }
    __syncthreads();
    if (tid < 64) {
        float s = sred[0][0][tid]+sred[0][1][tid]+sred[0][2][tid]+sred[0][3][tid];
        s_pn[tid] = (l > 0) ? rsqrtf(s*(1.0f/CC)+EPSF) : 1.0f;
    } else if (tid < 128) {
        const int j = tid-64;
        float s = sred[1][0][j]+sred[1][1][j]+sred[1][2][j]+sred[1][3][j];
        s_hn[j] = (t > 0) ? rsqrtf(s*(1.0f/CC)+EPSF) : 0.0f;
    }
    __syncthreads();

    // ---- phase 1b: reconstruct normalized y/hp; input-rms partials ----
    const float spn = s_pn[lane], shn = s_hn[lane];
    {
        float sy2 = 0.f, sh2 = 0.f;
        #pragma unroll
        for (int i = 0; i < 24; i++) {
            const int c = wv*24 + i;
            float yv = (l == 0) ? yr[i] : yr[i] * spn * onw_prev[c];
            float hv = hr[i] * shn * onw[c];
            yr[i] = yv; hr[i] = hv;
            sy2 += yv*yv; sh2 += hv*hv;
            // finalized normalized hp of layer 11 == final output at t-1
            if (l == LL-1 && half == 0 && t > 0)
                out[(((size_t)b*CC + c)*TT + (t-1))*FF + lane] = hv;
        }
        sred[0][wv][lane] = sy2;
        sred[1][wv][lane] = sh2;
    }
    __syncthreads();
    if (tid < 64) {
        float s = sred[0][0][tid]+sred[0][1][tid]+sred[0][2][tid]+sred[0][3][tid];
        sred[0][0][tid] = rsqrtf(s*(1.0f/CC)+EPSF);
    } else if (tid < 128) {
        const int j = tid-64;
        float s = sred[1][0][j]+sred[1][1][j]+sred[1][2][j]+sred[1][3][j];
        sred[1][0][j] = rsqrtf(s*(1.0f/CC)+EPSF);
    }
    __syncthreads();
    const float sy = sred[0][0][lane];
    const float sh = sred[1][0][lane];

    // ---- phase 2: dwconv (K=3) via lane shuffles; build Ay, Ah ----
    #pragma unroll
    for (int i = 0; i < 24; i++) {
        const int c = wv*24 + i;
        const float p1 = hr[i] * sh;
        float p0 = __shfl_up(p1, 1);   if (lane == 0)  p0 = 0.f;
        float p2 = __shfl_down(p1, 1); if (lane == 63) p2 = 0.f;
        Ah[c][lane] = (hw[c*3]*p0 + hw[c*3+1]*p1 + hw[c*3+2]*p2) * hnw[c] + hb[c];
        Ay[c][lane] = yr[i] * sy * inw[c];
    }
    __syncthreads();

    // ---- phase 3: matmuls (144 rows x 64 cols, K=96, x2), weights from L2 ----
    const int tx = tid & 15, ty = tid >> 4;
    const int j0 = tx * 4;
    const int r0 = ty * 3;
    const float* xwR = xw + (size_t)(ch0 + r0)*CC;   // + g*CC*CC + i*CC + kc
    const float* pwR = pw + (size_t)(ch0 + r0)*CC;

    float accx[3][3][4], accp[3][3][4];
    #pragma unroll
    for (int g = 0; g < 3; g++)
        #pragma unroll
        for (int i = 0; i < 3; i++)
            #pragma unroll
            for (int m = 0; m < 4; m++) { accx[g][i][m] = 0.f; accp[g][i][m] = 0.f; }

    #pragma unroll 2
    for (int kc = 0; kc < CC; kc += 4) {
        const float4 a0 = *(const float4*)&Ay[kc+0][j0];
        const float4 a1 = *(const float4*)&Ay[kc+1][j0];
        const float4 a2 = *(const float4*)&Ay[kc+2][j0];
        const float4 a3 = *(const float4*)&Ay[kc+3][j0];
        const float4 h0 = *(const float4*)&Ah[kc+0][j0];
        const float4 h1 = *(const float4*)&Ah[kc+1][j0];
        const float4 h2 = *(const float4*)&Ah[kc+2][j0];
        const float4 h3 = *(const float4*)&Ah[kc+3][j0];
        #pragma unroll
        for (int g = 0; g < 3; g++)
            #pragma unroll
            for (int i = 0; i < 3; i++) {
                const size_t off = (size_t)g*CC*CC + (size_t)i*CC + kc;
                const float4 wx  = *(const float4*)(xwR + off);
                const float4 wp4 = *(const float4*)(pwR + off);
                accx[g][i][0] += wx.x*a0.x + wx.y*a1.x + wx.z*a2.x + wx.w*a3.x;
                accx[g][i][1] += wx.x*a0.y + wx.y*a1.y + wx.z*a2.y + wx.w*a3.y;
                accx[g][i][2] += wx.x*a0.z + wx.y*a1.z + wx.z*a2.z + wx.w*a3.z;
                accx[g][i][3] += wx.x*a0.w + wx.y*a1.w + wx.z*a2.w + wx.w*a3.w;
                accp[g][i][0] += wp4.x*h0.x + wp4.y*h1.x + wp4.z*h2.x + wp4.w*h3.x;
                accp[g][i][1] += wp4.x*h0.y + wp4.y*h1.y + wp4.z*h2.y + wp4.w*h3.y;
                accp[g][i][2] += wp4.x*h0.z + wp4.y*h1.z + wp4.z*h2.z + wp4.w*h3.z;
                accp[g][i][3] += wp4.x*h0.w + wp4.y*h1.w + wp4.z*h2.w + wp4.w*h3.w;
            }
    }

    // ---- phase 4: GRU epilogue (in-register); write un-normalized v ----
    float sp4[4], sh4[4];
    #pragma unroll
    for (int m = 0; m < 4; m++) { sp4[m] = s_pn[j0+m]; sh4[m] = s_hn[j0+m]; }

    float* Hw = H + (((size_t)parW*LL + l)*BB + b)*CC*FF;
    #pragma unroll
    for (int i = 0; i < 3; i++) {
        const int co = ch0 + r0 + i;
        const float xbr = xb[co], xbz = xb[co+96], xbn = xb[co+192];
        const float pbr = pb[co], pbz = pb[co+96], pbn = pb[co+192];
        const float onwc = onw[co];
        const float opc  = (l > 0) ? onw_prev[co] : 1.0f;

        float y4[4], hp4[4];
        if (l == 0) {
            const float4 v = *(const float4*)(x + (((size_t)b*CC + co)*TT + t)*FF + j0);
            y4[0]=v.x; y4[1]=v.y; y4[2]=v.z; y4[3]=v.w;
        } else {
            const float4 v = *(const float4*)(Hprev + (size_t)co*FF + j0);
            y4[0]=v.x*sp4[0]*opc; y4[1]=v.y*sp4[1]*opc;
            y4[2]=v.z*sp4[2]*opc; y4[3]=v.w*sp4[3]*opc;
        }
        if (t > 0) {
            const float4 v = *(const float4*)(Hself + (size_t)co*FF + j0);
            hp4[0]=v.x*sh4[0]*onwc; hp4[1]=v.y*sh4[1]*onwc;
            hp4[2]=v.z*sh4[2]*onwc; hp4[3]=v.w*sh4[3]*onwc;
        } else {
            hp4[0]=hp4[1]=hp4[2]=hp4[3]=0.f;
        }

        float v4[4];
        #pragma unroll
        for (int m = 0; m < 4; m++) {
            const float r_ = sigmoidf_(accx[0][i][m] + xbr + accp[0][i][m] + pbr);
            const float z_ = sigmoidf_(accx[1][i][m] + xbz + accp[1][i][m] + pbz);
            const float cn = tanhf(accx[2][i][m] + xbn + r_ * (accp[2][i][m] + pbn));
            v4[m] = (1.f - z_)*cn + z_*hp4[m] + y4[m];
        }
        *(float4*)(Hw + (size_t)co*FF + j0) = make_float4(v4[0], v4[1], v4[2], v4[3]);
    }
}

// Emit out[:, :, TT-1, :] from the last diagonal's layer-11 state (parity 0).
__global__ __launch_bounds__(256) void finalize_last(
    const float* __restrict__ H,
    const float* __restrict__ onw_all,
    float* __restrict__ out)
{
    const int b = blockIdx.x;
    const int tid = threadIdx.x;
    const int lane = tid & 63;
    const int wv = tid >> 6;
    const float* onw = onw_all + (LL-1)*CC;
    const float* Hf  = H + (((size_t)0*LL + (LL-1))*BB + b)*CC*FF;  // parity 0

    __shared__ float sred[4][64];
    __shared__ float sf[64];

    float u[24]; float ss = 0.f;
    #pragma unroll
    for (int i = 0; i < 24; i++) {
        const int c = wv*24 + i;
        u[i] = Hf[(size_t)c*FF + lane];
        ss += u[i]*u[i];
    }
    sred[wv][lane] = ss;
    __syncthreads();
    if (tid < 64) {
        float s = sred[0][tid]+sred[1][tid]+sred[2][tid]+sred[3][tid];
        sf[tid] = rsqrtf(s*(1.0f/CC)+EPSF);
    }
    __syncthreads();
    const float s = sf[lane];
    #pragma unroll
    for (int i = 0; i < 24; i++) {
        const int c = wv*24 + i;
        out[(((size_t)b*CC + c)*TT + (TT-1))*FF + lane] = u[i] * s * onw[c];
    }
}

extern "C" void kernel_launch(void* const* d_in, const int* in_sizes, int n_in,
                              void* d_out, int out_size, void* d_ws, size_t ws_size,
                              hipStream_t stream) {
    const float* x   = (const float*)d_in[0];
    const float* inw = (const float*)d_in[1];
    const float* hnw = (const float*)d_in[2];
    const float* xw  = (const float*)d_in[3];
    const float* xb  = (const float*)d_in[4];
    const float* hw  = (const float*)d_in[5];
    const float* hb  = (const float*)d_in[6];
    const float* pw  = (const float*)d_in[7];
    const float* pb  = (const float*)d_in[8];
    const float* onw = (const float*)d_in[9];
    float* out = (float*)d_out;
    float* H   = (float*)d_ws;   // needs 2*LL*BB*CC*FF*4 = 4.72 MB

    // wavefront over anti-diagonals d = l + t
    for (int d = 0; d < TT + LL - 1; d++) {
        int l_lo = d - (TT - 1); if (l_lo < 0) l_lo = 0;
        int l_hi = d;            if (l_hi > LL - 1) l_hi = LL - 1;
        int nact = l_hi - l_lo + 1;
        cell_diag<<<dim3(nact * 16), dim3(256), 0, stream>>>(
            x, inw, hnw, xw, xb, hw, hb, pw, pb, onw, out, H, d, l_lo);
    }
    finalize_last<<<dim3(BB), dim3(256), 0, stream>>>(H, onw, out);
}